// Round 1
// baseline (559.148 us; speedup 1.0000x reference)
//
#include <hip/hip_runtime.h>
#include <cmath>

typedef _Float16 half_t;
typedef _Float16 half8 __attribute__((ext_vector_type(8)));
typedef _Float16 half4v __attribute__((ext_vector_type(4)));
typedef float float4v __attribute__((ext_vector_type(4)));

#define LOG2E 1.44269504088896340736f

// ---------------- cast fp32 -> fp16 ----------------
__global__ void cast_f32_f16(const float* __restrict__ in, half_t* __restrict__ out, int n) {
    int i = (blockIdx.x * blockDim.x + threadIdx.x) * 4;
    if (i >= n) return;
    float4 v = *(const float4*)(in + i);
    half4v o;
    o[0] = (half_t)v.x; o[1] = (half_t)v.y; o[2] = (half_t)v.z; o[3] = (half_t)v.w;
    *(half4v*)(out + i) = o;
}

// ---------------- transpose + cast: in fp32 [R][C] -> out fp16 [C][R] ----------------
__global__ void transpose_cast(const float* __restrict__ in, half_t* __restrict__ out, int R, int C) {
    __shared__ float tile[32][33];
    int c0 = blockIdx.x * 32, r0 = blockIdx.y * 32;
    int tx = threadIdx.x, ty = threadIdx.y; // block (32,8)
    for (int p = 0; p < 4; p++) {
        int r = r0 + ty + p * 8;
        tile[ty + p * 8][tx] = in[(size_t)r * C + c0 + tx];
    }
    __syncthreads();
    for (int p = 0; p < 4; p++) {
        int c = c0 + ty + p * 8;
        out[(size_t)c * R + r0 + tx] = (half_t)tile[tx][ty + p * 8];
    }
}

// ---------------- GEMM: C[M][N] = A[M][K] * Bt[N][K]^T + bias ----------------
// 128x128 tile, BK=32, 4 waves, each wave 64x64 via 4x4 frags of 16x16x32 f16 MFMA.
template <int OUT_F16>
__global__ __launch_bounds__(256) void gemm_f16(
    const half_t* __restrict__ A,   // [M][K]
    const half_t* __restrict__ Bt,  // [N][K]
    const float* __restrict__ bias, // [N]
    void* __restrict__ Cout,        // fp16 or fp32 [M][N]
    int M, int N, int K)
{
    __shared__ __align__(16) half_t As[128][40];
    __shared__ __align__(16) half_t Bs[128][40];
    int t = threadIdx.x;
    int lane = t & 63, w = t >> 6;
    int m0 = blockIdx.x * 128, n0 = blockIdx.y * 128;
    int wm = (w >> 1) * 64, wn = (w & 1) * 64;
    int row2 = t >> 2, coff = (t & 3) * 8;
    int lrow = lane & 15, quad = lane >> 4;

    float4v acc[4][4] = {};

    for (int k0 = 0; k0 < K; k0 += 32) {
        __syncthreads();
        *(uint4*)(&As[row2][coff])      = *(const uint4*)(A  + (size_t)(m0 + row2)      * K + k0 + coff);
        *(uint4*)(&As[row2 + 64][coff]) = *(const uint4*)(A  + (size_t)(m0 + row2 + 64) * K + k0 + coff);
        *(uint4*)(&Bs[row2][coff])      = *(const uint4*)(Bt + (size_t)(n0 + row2)      * K + k0 + coff);
        *(uint4*)(&Bs[row2 + 64][coff]) = *(const uint4*)(Bt + (size_t)(n0 + row2 + 64) * K + k0 + coff);
        __syncthreads();
        half8 af[4], bf[4];
        for (int i = 0; i < 4; i++) af[i] = *(const half8*)(&As[wm + i * 16 + lrow][quad * 8]);
        for (int i = 0; i < 4; i++) bf[i] = *(const half8*)(&Bs[wn + i * 16 + lrow][quad * 8]);
        for (int mi = 0; mi < 4; mi++)
            for (int ni = 0; ni < 4; ni++)
                acc[mi][ni] = __builtin_amdgcn_mfma_f32_16x16x32_f16(af[mi], bf[ni], acc[mi][ni], 0, 0, 0);
    }

    for (int mi = 0; mi < 4; mi++)
        for (int ni = 0; ni < 4; ni++)
            for (int r = 0; r < 4; r++) {
                int gr = m0 + wm + mi * 16 + quad * 4 + r;
                int gc = n0 + wn + ni * 16 + lrow;
                float v = acc[mi][ni][r] + bias[gc];
                if (OUT_F16) ((half_t*)Cout)[(size_t)gr * N + gc] = (half_t)v;
                else         ((float*)Cout)[(size_t)gr * N + gc] = v;
            }
}

// ---------------- RMSNorm on q,k heads + relayout to [bh][s][d] ----------------
__global__ void rmsnorm_qk(const half_t* __restrict__ qkv,
                           const float* __restrict__ wq, const float* __restrict__ wk,
                           half_t* __restrict__ Qh, half_t* __restrict__ Kh) {
    int row = blockIdx.x;          // 0..8191 = b*2048+s
    int b = row >> 11, s = row & 2047;
    int t = threadIdx.x;           // 0..127
    int isK = t >> 6;
    int tt = t & 63;
    int head = tt >> 2, chunk = tt & 3;
    const half_t* src = qkv + (size_t)row * 3072 + isK * 1024 + head * 64 + chunk * 16;
    half8 h0 = *(const half8*)(src);
    half8 h1 = *(const half8*)(src + 8);
    float v[16];
    for (int i = 0; i < 8; i++) { v[i] = (float)h0[i]; v[8 + i] = (float)h1[i]; }
    float ss = 0.f;
    for (int i = 0; i < 16; i++) ss += v[i] * v[i];
    ss += __shfl_xor(ss, 1);
    ss += __shfl_xor(ss, 2);
    float rr = rsqrtf(ss * (1.0f / 64.0f) + 1e-6f);
    const float* wv = (isK ? wk : wq) + chunk * 16;
    half_t* dst = (isK ? Kh : Qh) + ((size_t)((b * 16 + head) * 2048 + s)) * 64 + chunk * 16;
    half8 o0, o1;
    for (int i = 0; i < 8; i++) {
        o0[i] = (half_t)(v[i] * rr * wv[i]);
        o1[i] = (half_t)(v[8 + i] * rr * wv[8 + i]);
    }
    *(half8*)(dst) = o0;
    *(half8*)(dst + 8) = o1;
}

// ---------------- V relayout: qkv v-part [b,s,h,d] -> Vt [bh][d][s] ----------------
__global__ void v_transpose(const half_t* __restrict__ qkv, half_t* __restrict__ Vt) {
    __shared__ half_t tile[32][40];
    int s0 = blockIdx.x * 32;
    int d0 = blockIdx.y * 32;
    int bh = blockIdx.z;
    int b = bh >> 4, h = bh & 15;
    int tx = threadIdx.x, ty = threadIdx.y; // (32,8)
    for (int p = 0; p < 4; p++) {
        int s = s0 + ty + p * 8;
        tile[ty + p * 8][tx] = qkv[((size_t)(b * 2048 + s)) * 3072 + 2048 + h * 64 + d0 + tx];
    }
    __syncthreads();
    for (int p = 0; p < 4; p++) {
        int d = d0 + ty + p * 8;
        Vt[((size_t)bh * 64 + d) * 2048 + s0 + tx] = tile[tx][ty + p * 8];
    }
}

// ---------------- Flash attention, causal, no scale ----------------
// grid (32 qtiles, 64 bh), block 256 = 4 waves; wave w: q rows qb+16w..+15.
__global__ __launch_bounds__(256) void attn(
    const half_t* __restrict__ Qh, const half_t* __restrict__ Kh, const half_t* __restrict__ Vt,
    half_t* __restrict__ Z)
{
    __shared__ __align__(16) half_t Ks[32][72];
    __shared__ __align__(16) half_t Vs[64][40];
    __shared__ __align__(16) half_t Ps[4][16][40];

    int qt = blockIdx.x;
    int bh = blockIdx.y;
    int b = bh >> 4, h = bh & 15;
    int t = threadIdx.x, lane = t & 63, w = t >> 6;
    int lrow = lane & 15, quad = lane >> 4;
    int qb = qt * 64;
    int q0w = qb + w * 16;

    const half_t* Qbase = Qh + ((size_t)bh * 2048 + q0w + lrow) * 64;
    half8 qf0 = *(const half8*)(Qbase + quad * 8);
    half8 qf1 = *(const half8*)(Qbase + 32 + quad * 8);

    float4v o0 = {}, o1 = {}, o2 = {}, o3 = {};
    float m[4], l[4];
    for (int r = 0; r < 4; r++) { m[r] = -__builtin_inff(); l[r] = 0.f; }

    int nt = 2 * qt + 2;
    for (int kt = 0; kt < nt; kt++) {
        __syncthreads();
        {   // stage K tile [32][64]
            int r = t >> 3, c = (t & 7) * 8;
            *(uint4*)(&Ks[r][c]) = *(const uint4*)(Kh + ((size_t)bh * 2048 + kt * 32 + r) * 64 + c);
        }
        {   // stage V^T tile [64][32]
            int r = t >> 2, c = (t & 3) * 8;
            *(uint4*)(&Vs[r][c]) = *(const uint4*)(Vt + ((size_t)bh * 64 + r) * 2048 + kt * 32 + c);
        }
        __syncthreads();
        if (kt * 32 > q0w + 15) continue;   // fully masked for this wave

        // QK^T: S[16 q][32 keys]
        float4v s0 = {}, s1 = {};
        {
            half8 k00 = *(const half8*)(&Ks[lrow][quad * 8]);
            half8 k01 = *(const half8*)(&Ks[lrow][32 + quad * 8]);
            half8 k10 = *(const half8*)(&Ks[16 + lrow][quad * 8]);
            half8 k11 = *(const half8*)(&Ks[16 + lrow][32 + quad * 8]);
            s0 = __builtin_amdgcn_mfma_f32_16x16x32_f16(qf0, k00, s0, 0, 0, 0);
            s0 = __builtin_amdgcn_mfma_f32_16x16x32_f16(qf1, k01, s0, 0, 0, 0);
            s1 = __builtin_amdgcn_mfma_f32_16x16x32_f16(qf0, k10, s1, 0, 0, 0);
            s1 = __builtin_amdgcn_mfma_f32_16x16x32_f16(qf1, k11, s1, 0, 0, 0);
        }
        // mask + online softmax (C layout: row=quad*4+r, col=f*16+lrow)
        float sv[2][4];
        for (int r = 0; r < 4; r++) { sv[0][r] = s0[r]; sv[1][r] = s1[r]; }
        for (int f = 0; f < 2; f++)
            for (int r = 0; r < 4; r++) {
                int key = kt * 32 + f * 16 + lrow;
                int q = q0w + quad * 4 + r;
                if (key > q) sv[f][r] = -__builtin_inff();
            }
        float alpha[4], pr[2][4];
        for (int r = 0; r < 4; r++) {
            float tm = fmaxf(sv[0][r], sv[1][r]);
            tm = fmaxf(tm, __shfl_xor(tm, 1));
            tm = fmaxf(tm, __shfl_xor(tm, 2));
            tm = fmaxf(tm, __shfl_xor(tm, 4));
            tm = fmaxf(tm, __shfl_xor(tm, 8));
            float mn = fmaxf(m[r], tm);
            alpha[r] = exp2f((m[r] - mn) * LOG2E);
            m[r] = mn;
            float p0 = exp2f((sv[0][r] - mn) * LOG2E);
            float p1 = exp2f((sv[1][r] - mn) * LOG2E);
            pr[0][r] = p0; pr[1][r] = p1;
            float rs = p0 + p1;
            rs += __shfl_xor(rs, 1);
            rs += __shfl_xor(rs, 2);
            rs += __shfl_xor(rs, 4);
            rs += __shfl_xor(rs, 8);
            l[r] = l[r] * alpha[r] + rs;
        }
        for (int r = 0; r < 4; r++) { o0[r] *= alpha[r]; o1[r] *= alpha[r]; o2[r] *= alpha[r]; o3[r] *= alpha[r]; }
        // P: C layout -> A layout via per-wave LDS
        for (int f = 0; f < 2; f++)
            for (int r = 0; r < 4; r++)
                Ps[w][quad * 4 + r][f * 16 + lrow] = (half_t)pr[f][r];
        __asm__ volatile("s_waitcnt lgkmcnt(0)" ::: "memory");
        half8 pa = *(const half8*)(&Ps[w][lrow][quad * 8]);
        // PV: O[16 q][64 d]
        half8 v0 = *(const half8*)(&Vs[lrow][quad * 8]);
        half8 v1 = *(const half8*)(&Vs[16 + lrow][quad * 8]);
        half8 v2 = *(const half8*)(&Vs[32 + lrow][quad * 8]);
        half8 v3 = *(const half8*)(&Vs[48 + lrow][quad * 8]);
        o0 = __builtin_amdgcn_mfma_f32_16x16x32_f16(pa, v0, o0, 0, 0, 0);
        o1 = __builtin_amdgcn_mfma_f32_16x16x32_f16(pa, v1, o1, 0, 0, 0);
        o2 = __builtin_amdgcn_mfma_f32_16x16x32_f16(pa, v2, o2, 0, 0, 0);
        o3 = __builtin_amdgcn_mfma_f32_16x16x32_f16(pa, v3, o3, 0, 0, 0);
    }

    for (int r = 0; r < 4; r++) {
        int s = qb + w * 16 + quad * 4 + r;
        float inv = 1.0f / l[r];
        size_t base = ((size_t)(b * 2048 + s)) * 1024 + h * 64;
        Z[base +  0 + lrow] = (half_t)(o0[r] * inv);
        Z[base + 16 + lrow] = (half_t)(o1[r] * inv);
        Z[base + 32 + lrow] = (half_t)(o2[r] * inv);
        Z[base + 48 + lrow] = (half_t)(o3[r] * inv);
    }
}

// ---------------- launch ----------------
extern "C" void kernel_launch(void* const* d_in, const int* in_sizes, int n_in,
                              void* d_out, int out_size, void* d_ws, size_t ws_size,
                              hipStream_t stream)
{
    const float* x     = (const float*)d_in[0];
    // d_in[1] = mask (causal, known analytically) - unused
    const float* W_qkv = (const float*)d_in[2];
    const float* b_qkv = (const float*)d_in[3];
    const float* W_o   = (const float*)d_in[4];
    const float* b_o   = (const float*)d_in[5];
    const float* wq    = (const float*)d_in[6];
    const float* wk    = (const float*)d_in[7];
    float* out = (float*)d_out;

    char* ws = (char*)d_ws;
    half_t* xh  = (half_t*)(ws);                      // 16 MB (reused as zh after GEMM1)
    half_t* Wqt = (half_t*)(ws + (16ull << 20));      // 6 MB
    half_t* Wot = (half_t*)(ws + (22ull << 20));      // 2 MB
    half_t* qkv = (half_t*)(ws + (24ull << 20));      // 48 MB
    half_t* Qh  = (half_t*)(ws + (72ull << 20));      // 16 MB
    half_t* Kh  = (half_t*)(ws + (88ull << 20));      // 16 MB
    half_t* Vt  = (half_t*)(ws + (104ull << 20));     // 16 MB
    half_t* zh  = xh;

    cast_f32_f16<<<8192, 256, 0, stream>>>(x, xh, 8192 * 1024);
    transpose_cast<<<dim3(96, 32), dim3(32, 8), 0, stream>>>(W_qkv, Wqt, 1024, 3072);
    transpose_cast<<<dim3(32, 32), dim3(32, 8), 0, stream>>>(W_o, Wot, 1024, 1024);
    gemm_f16<1><<<dim3(64, 24), 256, 0, stream>>>(xh, Wqt, b_qkv, qkv, 8192, 3072, 1024);
    rmsnorm_qk<<<8192, 128, 0, stream>>>(qkv, wq, wk, Qh, Kh);
    v_transpose<<<dim3(64, 2, 64), dim3(32, 8), 0, stream>>>(qkv, Vt);
    attn<<<dim3(32, 64), 256, 0, stream>>>(Qh, Kh, Vt, zh);
    gemm_f16<0><<<dim3(64, 8), 256, 0, stream>>>(zh, Wot, b_o, out, 8192, 1024, 1024);
}

// Round 2
// 322.737 us; speedup vs baseline: 1.7325x; 1.7325x over previous
//
#include <hip/hip_runtime.h>
#include <cmath>

typedef _Float16 half_t;
typedef _Float16 half8 __attribute__((ext_vector_type(8)));
typedef _Float16 half4v __attribute__((ext_vector_type(4)));
typedef float float4v __attribute__((ext_vector_type(4)));

#define LOG2E 1.44269504088896340736f

#define GLDS16(g, l)                                                                   \
    __builtin_amdgcn_global_load_lds((const __attribute__((address_space(1))) void*)(g), \
                                     (__attribute__((address_space(3))) void*)(l), 16, 0, 0)

// ---------------- cast fp32 -> fp16 ----------------
__global__ void cast_f32_f16(const float* __restrict__ in, half_t* __restrict__ out, int n) {
    int i = (blockIdx.x * blockDim.x + threadIdx.x) * 4;
    if (i >= n) return;
    float4 v = *(const float4*)(in + i);
    half4v o;
    o[0] = (half_t)v.x; o[1] = (half_t)v.y; o[2] = (half_t)v.z; o[3] = (half_t)v.w;
    *(half4v*)(out + i) = o;
}

// ---------------- transpose + cast: in fp32 [R][C] -> out fp16 [C][R] ----------------
__global__ void transpose_cast(const float* __restrict__ in, half_t* __restrict__ out, int R, int C) {
    __shared__ float tile[32][33];
    int c0 = blockIdx.x * 32, r0 = blockIdx.y * 32;
    int tx = threadIdx.x, ty = threadIdx.y; // block (32,8)
    for (int p = 0; p < 4; p++) {
        int r = r0 + ty + p * 8;
        tile[ty + p * 8][tx] = in[(size_t)r * C + c0 + tx];
    }
    __syncthreads();
    for (int p = 0; p < 4; p++) {
        int c = c0 + ty + p * 8;
        out[(size_t)c * R + r0 + tx] = (half_t)tile[tx][ty + p * 8];
    }
}

// ---------------- GEMM: C[M][N] = A[M][K] * Bt[N][K]^T + bias ----------------
// 128x128 tile, BK=32, 4 waves; m97-style global_load_lds width-16 staging.
template <int OUT_F16>
__global__ __launch_bounds__(256) void gemm_f16(
    const half_t* __restrict__ A,   // [M][K]
    const half_t* __restrict__ Bt,  // [N][K]
    const float* __restrict__ bias, // [N]
    void* __restrict__ Cout,        // fp16 or fp32 [M][N]
    int M, int N, int K)
{
    __shared__ __align__(16) half_t As[128 * 32];
    __shared__ __align__(16) half_t Bs[128 * 32];
    int t = threadIdx.x;
    int lane = t & 63, w = t >> 6;
    int m0 = blockIdx.x * 128, n0 = blockIdx.y * 128;
    int wm = (w >> 1) * 64, wn = (w & 1) * 64;
    int lrow = lane & 15, quad = lane >> 4;

    // staging: thread t covers (row = t>>2, col = (t&3)*8 halves); LDS offset = t*16B (linear)
    int srow = t >> 2, scol = (t & 3) * 8;
    const half_t* gA = A  + (size_t)(m0 + srow) * K + scol;
    const half_t* gB = Bt + (size_t)(n0 + srow) * K + scol;
    half_t* ldsA = As + w * 512;   // wave-uniform base, lane*16B implicit
    half_t* ldsB = Bs + w * 512;

    float4v acc[4][4] = {};

    for (int k0 = 0; k0 < K; k0 += 32) {
        __syncthreads();
        GLDS16(gA + k0,               ldsA);
        GLDS16(gA + (size_t)64 * K + k0, ldsA + 2048);
        GLDS16(gB + k0,               ldsB);
        GLDS16(gB + (size_t)64 * K + k0, ldsB + 2048);
        __asm__ volatile("s_waitcnt vmcnt(0)" ::: "memory");
        __syncthreads();
        half8 af[4], bf[4];
        for (int i = 0; i < 4; i++) af[i] = *(const half8*)(&As[(wm + i * 16 + lrow) * 32 + quad * 8]);
        for (int i = 0; i < 4; i++) bf[i] = *(const half8*)(&Bs[(wn + i * 16 + lrow) * 32 + quad * 8]);
        for (int mi = 0; mi < 4; mi++)
            for (int ni = 0; ni < 4; ni++)
                acc[mi][ni] = __builtin_amdgcn_mfma_f32_16x16x32_f16(af[mi], bf[ni], acc[mi][ni], 0, 0, 0);
    }

    for (int mi = 0; mi < 4; mi++)
        for (int ni = 0; ni < 4; ni++)
            for (int r = 0; r < 4; r++) {
                int gr = m0 + wm + mi * 16 + quad * 4 + r;
                int gc = n0 + wn + ni * 16 + lrow;
                float v = acc[mi][ni][r] + bias[gc];
                if (OUT_F16) ((half_t*)Cout)[(size_t)gr * N + gc] = (half_t)v;
                else         ((float*)Cout)[(size_t)gr * N + gc] = v;
            }
}

// ---------------- RMSNorm on q,k heads + relayout to [bh][s][d] ----------------
__global__ void rmsnorm_qk(const half_t* __restrict__ qkv,
                           const float* __restrict__ wq, const float* __restrict__ wk,
                           half_t* __restrict__ Qh, half_t* __restrict__ Kh) {
    int row = blockIdx.x;          // 0..8191 = b*2048+s
    int b = row >> 11, s = row & 2047;
    int t = threadIdx.x;           // 0..127
    int isK = t >> 6;
    int tt = t & 63;
    int head = tt >> 2, chunk = tt & 3;
    const half_t* src = qkv + (size_t)row * 3072 + isK * 1024 + head * 64 + chunk * 16;
    half8 h0 = *(const half8*)(src);
    half8 h1 = *(const half8*)(src + 8);
    float v[16];
    for (int i = 0; i < 8; i++) { v[i] = (float)h0[i]; v[8 + i] = (float)h1[i]; }
    float ss = 0.f;
    for (int i = 0; i < 16; i++) ss += v[i] * v[i];
    ss += __shfl_xor(ss, 1);
    ss += __shfl_xor(ss, 2);
    float rr = rsqrtf(ss * (1.0f / 64.0f) + 1e-6f);
    const float* wv = (isK ? wk : wq) + chunk * 16;
    half_t* dst = (isK ? Kh : Qh) + ((size_t)((b * 16 + head) * 2048 + s)) * 64 + chunk * 16;
    half8 o0, o1;
    for (int i = 0; i < 8; i++) {
        o0[i] = (half_t)(v[i] * rr * wv[i]);
        o1[i] = (half_t)(v[8 + i] * rr * wv[8 + i]);
    }
    *(half8*)(dst) = o0;
    *(half8*)(dst + 8) = o1;
}

// ---------------- V relayout: qkv v-part [b,s,h,d] -> Vt [bh][d][s] ----------------
__global__ void v_transpose(const half_t* __restrict__ qkv, half_t* __restrict__ Vt) {
    __shared__ half_t tile[32][40];
    int s0 = blockIdx.x * 32;
    int d0 = blockIdx.y * 32;
    int bh = blockIdx.z;
    int b = bh >> 4, h = bh & 15;
    int tx = threadIdx.x, ty = threadIdx.y; // (32,8)
    for (int p = 0; p < 4; p++) {
        int s = s0 + ty + p * 8;
        tile[ty + p * 8][tx] = qkv[((size_t)(b * 2048 + s)) * 3072 + 2048 + h * 64 + d0 + tx];
    }
    __syncthreads();
    for (int p = 0; p < 4; p++) {
        int d = d0 + ty + p * 8;
        Vt[((size_t)bh * 64 + d) * 2048 + s0 + tx] = tile[tx][ty + p * 8];
    }
}

// ---------------- Flash attention, causal, no scale ----------------
// S^T = K Q^T formulation: row-softmax stats live in the lane (q = lane&15),
// only 2 shfls per 64-key tile. Blocks pair q-tiles (i, 31-i) -> uniform 33 iters.
// grid (16 pairs, 64 bh), block 256 = 4 waves; wave w: q rows qb+16w..+15.
__global__ __launch_bounds__(256, 4) void attn(
    const half_t* __restrict__ Qh, const half_t* __restrict__ Kh, const half_t* __restrict__ Vt,
    half_t* __restrict__ Z)
{
    __shared__ __align__(16) half_t Ks[64][88];   // [key][d]
    __shared__ __align__(16) half_t Vs[64][88];   // [d][key]
    __shared__ __align__(16) half_t Ps[4][16][88]; // per-wave [q][key]

    int bh = blockIdx.y;
    int b = bh >> 4, h = bh & 15;
    int t = threadIdx.x, lane = t & 63, w = t >> 6;
    int lrow = lane & 15, quad = lane >> 4;

    for (int pass = 0; pass < 2; pass++) {
        int qt = pass ? (31 - (int)blockIdx.x) : (int)blockIdx.x;
        int qb = qt * 64;
        int q0w = qb + w * 16;

        // Q fragment (B-operand): rows q, k-dim = d
        const half_t* Qbase = Qh + ((size_t)bh * 2048 + q0w + lrow) * 64;
        half8 qf0 = *(const half8*)(Qbase + quad * 8);
        half8 qf1 = *(const half8*)(Qbase + 32 + quad * 8);

        float4v ot[4] = {};                 // O^T: rows d (16 per frag), col q = lrow
        float m = -__builtin_inff(), l = 0.f;

        for (int kt = 0; kt <= qt; kt++) {
            int kb = kt * 64;
            __syncthreads();
            for (int j = 0; j < 2; j++) {
                int r = (t >> 3) + 32 * j, c = (t & 7) * 8;
                *(uint4*)(&Ks[r][c]) = *(const uint4*)(Kh + ((size_t)bh * 2048 + kb + r) * 64 + c);
                *(uint4*)(&Vs[r][c]) = *(const uint4*)(Vt + ((size_t)bh * 64 + r) * 2048 + kb + c);
            }
            __syncthreads();

            // S^T = K Q^T : st[f] rows = keys kb+16f+quad*4+r, col q = lrow
            float4v st[4];
            for (int f = 0; f < 4; f++) {
                float4v z = {};
                half8 k0 = *(const half8*)(&Ks[f * 16 + lrow][quad * 8]);
                half8 k1 = *(const half8*)(&Ks[f * 16 + lrow][32 + quad * 8]);
                z = __builtin_amdgcn_mfma_f32_16x16x32_f16(k0, qf0, z, 0, 0, 0);
                z = __builtin_amdgcn_mfma_f32_16x16x32_f16(k1, qf1, z, 0, 0, 0);
                st[f] = z;
            }
            if (kt == qt) {  // diagonal tile: causal mask
                int qrel = w * 16 + lrow;
                for (int f = 0; f < 4; f++)
                    for (int r = 0; r < 4; r++) {
                        int krel = f * 16 + quad * 4 + r;
                        if (krel > qrel) st[f][r] = -__builtin_inff();
                    }
            }
            // online softmax: in-lane over 16 values + 2 shfls across quads
            float tm = st[0][0];
            for (int f = 0; f < 4; f++)
                for (int r = 0; r < 4; r++) tm = fmaxf(tm, st[f][r]);
            tm = fmaxf(tm, __shfl_xor(tm, 16));
            tm = fmaxf(tm, __shfl_xor(tm, 32));
            float mn = fmaxf(m, tm);
            float alpha = exp2f((m - mn) * LOG2E);
            m = mn;
            float rs = 0.f;
            for (int f = 0; f < 4; f++) {
                half4v ph;
                for (int r = 0; r < 4; r++) {
                    float p = exp2f((st[f][r] - mn) * LOG2E);
                    rs += p;
                    ph[r] = (half_t)p;
                }
                *(half4v*)(&Ps[w][lrow][f * 16 + quad * 4]) = ph;
            }
            rs += __shfl_xor(rs, 16);
            rs += __shfl_xor(rs, 32);
            l = l * alpha + rs;
            for (int f2 = 0; f2 < 4; f2++)
                for (int r = 0; r < 4; r++) ot[f2][r] *= alpha;

            __asm__ volatile("s_waitcnt lgkmcnt(0)" ::: "memory");
            half8 p0 = *(const half8*)(&Ps[w][lrow][quad * 8]);
            half8 p1 = *(const half8*)(&Ps[w][lrow][32 + quad * 8]);
            // O^T += V^T P^T : A = V^T rows d, B = P rows q
            for (int f2 = 0; f2 < 4; f2++) {
                half8 v0 = *(const half8*)(&Vs[f2 * 16 + lrow][quad * 8]);
                half8 v1 = *(const half8*)(&Vs[f2 * 16 + lrow][32 + quad * 8]);
                ot[f2] = __builtin_amdgcn_mfma_f32_16x16x32_f16(v0, p0, ot[f2], 0, 0, 0);
                ot[f2] = __builtin_amdgcn_mfma_f32_16x16x32_f16(v1, p1, ot[f2], 0, 0, 0);
            }
        }

        float inv = 1.0f / l;
        size_t base = ((size_t)(b * 2048) + q0w + lrow) * 1024 + h * 64;
        for (int f2 = 0; f2 < 4; f2++) {
            half4v oh;
            for (int r = 0; r < 4; r++) oh[r] = (half_t)(ot[f2][r] * inv);
            *(half4v*)(Z + base + f2 * 16 + quad * 4) = oh;
        }
    }
}

// ---------------- launch ----------------
extern "C" void kernel_launch(void* const* d_in, const int* in_sizes, int n_in,
                              void* d_out, int out_size, void* d_ws, size_t ws_size,
                              hipStream_t stream)
{
    const float* x     = (const float*)d_in[0];
    // d_in[1] = mask (causal, known analytically) - unused
    const float* W_qkv = (const float*)d_in[2];
    const float* b_qkv = (const float*)d_in[3];
    const float* W_o   = (const float*)d_in[4];
    const float* b_o   = (const float*)d_in[5];
    const float* wq    = (const float*)d_in[6];
    const float* wk    = (const float*)d_in[7];
    float* out = (float*)d_out;

    char* ws = (char*)d_ws;
    half_t* xh  = (half_t*)(ws);                      // 16 MB (reused as zh after GEMM1)
    half_t* Wqt = (half_t*)(ws + (16ull << 20));      // 6 MB
    half_t* Wot = (half_t*)(ws + (22ull << 20));      // 2 MB
    half_t* qkv = (half_t*)(ws + (24ull << 20));      // 48 MB
    half_t* Qh  = (half_t*)(ws + (72ull << 20));      // 16 MB
    half_t* Kh  = (half_t*)(ws + (88ull << 20));      // 16 MB
    half_t* Vt  = (half_t*)(ws + (104ull << 20));     // 16 MB
    half_t* zh  = xh;

    cast_f32_f16<<<8192, 256, 0, stream>>>(x, xh, 8192 * 1024);
    transpose_cast<<<dim3(96, 32), dim3(32, 8), 0, stream>>>(W_qkv, Wqt, 1024, 3072);
    transpose_cast<<<dim3(32, 32), dim3(32, 8), 0, stream>>>(W_o, Wot, 1024, 1024);
    gemm_f16<1><<<dim3(64, 24), 256, 0, stream>>>(xh, Wqt, b_qkv, qkv, 8192, 3072, 1024);
    rmsnorm_qk<<<8192, 128, 0, stream>>>(qkv, wq, wk, Qh, Kh);
    v_transpose<<<dim3(64, 2, 64), dim3(32, 8), 0, stream>>>(qkv, Vt);
    attn<<<dim3(16, 64), 256, 0, stream>>>(Qh, Kh, Vt, zh);
    gemm_f16<0><<<dim3(64, 8), 256, 0, stream>>>(zh, Wot, b_o, out, 8192, 1024, 1024);
}